// Round 11
// baseline (201.786 us; speedup 1.0000x reference)
//
#include <hip/hip_runtime.h>
#include <hip/hip_fp16.h>

// GCN 3-layer, CSR-gather, low-rank L1 + fused L2/L3 transform.
//   CSR build GLOBAL-ATOMIC-FREE (two-level counting sort, LDS atomics only).
//   R10: scan_scatter absorbs (a) dst-side fine-hist (row_off = bbase_d[b] +
//     local prefix — bbase_d[b] IS the global edge prefix, bsum/pb-scan dead),
//     (b) the h1 layer: S@T1t MFMA straight from LDS Sl (fp32->fp16 at same
//     rounding point -> bitwise-identical h1s). S global round-trip + h1_mfma
//     + fine_hist-dst eliminated; 9 -> 7 launches. R9 degree-sort removed (null).
//   R8: layer-1 low-rank over labels (S[n][l] = sum out_norm over in-edges).
//   L2+L3 fused: agg -> LDS fp16 A, MFMA 16x16x32_f16 (fp32 acc),
//     W2t/W3t fp16 LDS stride 104, h2 in-place per-wave, t fp16 stride 64
//     in bufA (disjoint from h1s — R6 race fix).
//   out = in_norm*gather(t fp16) + b3
#define N_NODES 50000
#define N_EDGES 800000
#define EMB     64
#define HID     96
#define NLAB    50
#define TSTRIDE 64                         // t row stride (halfs): 128B line-aligned
#define TC      13                         // gather chunks over t (cols 0..51)
#define NBP     256                        // partition blocks
#define EPB     ((N_EDGES + NBP - 1) / NBP)  // 3125 edges per block
#define NBUCK   196                        // node buckets of 256 (covers 50176)
#define WSTRIDE 104                        // W2t/W3t/A LDS row stride (halfs)
#define WPREP_N (160 * WSTRIDE)            // 96 W2t rows + 64 W3t rows
#define WPREPB  ((WPREP_N + 255) / 256)    // 65
#define T1TSTR  72                         // T1t row stride (halfs)
#define T1T_N   (HID * T1TSTR)             // 96 rows x 72
#define T1TB    ((T1T_N + 255) / 256)      // 27
#define NMFMA   ((N_NODES + 127) / 128)    // 392 blocks of 128 nodes

typedef _Float16 f16x8 __attribute__((ext_vector_type(8)));
typedef float f32x4 __attribute__((ext_vector_type(4)));

__device__ __forceinline__ float2 h2f(unsigned u) {
    __half2 h = *reinterpret_cast<__half2*>(&u);
    return __half22float2(h);
}
__device__ __forceinline__ unsigned f2h(float a, float b) {
    __half2 h = __floats2half2_rn(a, b);
    return *reinterpret_cast<unsigned*>(&h);
}

// Per-block coarse histograms (dst>>8, src>>8) via LDS atomics. Tail blocks:
// T1t[j][l] = (emb@W1)^T fp16 (stride 72, l>=50 zero), then W2t/W3t prep.
__global__ void coarse_hist_kernel(const int* __restrict__ src, const int* __restrict__ dst,
                                   int* __restrict__ histd, int* __restrict__ hists,
                                   const float* __restrict__ emb, const float* __restrict__ W1,
                                   __half* __restrict__ T1t,
                                   const float* __restrict__ W2, const float* __restrict__ W3,
                                   __half* __restrict__ wprep) {
    int b = blockIdx.x, t = threadIdx.x;
    if (b < NBP) {
        __shared__ int hd[256], hs[256];
        hd[t] = 0; hs[t] = 0;
        __syncthreads();
        int hi = min(b * EPB + EPB, N_EDGES);
        for (int i = b * EPB + t; i < hi; i += 256) {
            atomicAdd(&hd[((unsigned)dst[i]) >> 8], 1);
            atomicAdd(&hs[((unsigned)src[i]) >> 8], 1);
        }
        __syncthreads();
        histd[b * 256 + t] = hd[t];
        hists[b * 256 + t] = hs[t];
    } else if (b < NBP + T1TB) {
        int i = (b - NBP) * 256 + t;
        if (i < T1T_N) {
            int j = i / T1TSTR, l = i - j * T1TSTR;
            float sum = 0.0f;
            if (l < NLAB) {
#pragma unroll
                for (int m = 0; m < EMB; ++m) sum += emb[l * EMB + m] * W1[m * HID + j];
            }
            T1t[i] = __float2half(sum);
        }
    } else {
        // wprep rows 0..95: W2t (j over HID); rows 96..159: W3t (j over 64)
        int i = (b - NBP - T1TB) * 256 + t;
        if (i < WPREP_N) {
            int j = i / WSTRIDE, kk = i - j * WSTRIDE;
            float v = 0.0f;
            if (kk < HID) {
                if (j < HID) v = W2[kk * HID + j];
                else { int jj = j - HID; if (jj < NLAB) v = W3[kk * NLAB + jj]; }
            }
            wprep[i] = __float2half(v);
        }
    }
}

// Block 0: dst side; block 1: src side. Thread t owns bucket t.
__global__ void coarse_scan_kernel(const int* __restrict__ histd, const int* __restrict__ hists,
                                   int* __restrict__ blkrel_d, int* __restrict__ blkrel_s,
                                   int* __restrict__ bbase_d, int* __restrict__ bbase_s) {
    __shared__ int sh[256];
    int t = threadIdx.x;
    const int* hist = blockIdx.x ? hists : histd;
    int* blkrel     = blockIdx.x ? blkrel_s : blkrel_d;
    int* bbase      = blockIdx.x ? bbase_s : bbase_d;
    int run = 0;
#pragma unroll 16
    for (int b = 0; b < NBP; ++b) {
        blkrel[b * 256 + t] = run;
        run += hist[b * 256 + t];
    }
    sh[t] = run;
    __syncthreads();
    for (int off = 1; off < 256; off <<= 1) {
        int v = sh[t];
        if (t >= off) v += sh[t - off];
        __syncthreads();
        sh[t] = v;
        __syncthreads();
    }
    bbase[t] = sh[t] - run;   // exclusive bucket base
}

// Scatter edges into bucket-partitioned arrays via LDS cursors (no global RMW).
// dstp rec = src | (dst&255)<<16 ; srcp rec = (byte) src&255.
__global__ void partition_kernel(const int* __restrict__ src, const int* __restrict__ dst,
                                 const int* __restrict__ blkrel_d, const int* __restrict__ blkrel_s,
                                 const int* __restrict__ bbase_d, const int* __restrict__ bbase_s,
                                 int* __restrict__ dstp, unsigned char* __restrict__ srcp) {
    __shared__ int curd[256], curs[256];
    int b = blockIdx.x, t = threadIdx.x;
    curd[t] = bbase_d[t] + blkrel_d[b * 256 + t];
    curs[t] = bbase_s[t] + blkrel_s[b * 256 + t];
    __syncthreads();
    int hi = min(b * EPB + EPB, N_EDGES);
    for (int i = b * EPB + t; i < hi; i += 256) {
        int d = dst[i], s = src[i];
        int pd = atomicAdd(&curd[((unsigned)d) >> 8], 1);
        dstp[pd] = s | ((d & 0xFF) << 16);
        int ps = atomicAdd(&curs[((unsigned)s) >> 8], 1);
        srcp[ps] = (unsigned char)(s & 0xFF);
    }
}

// Src-side fine histogram only: deg_out -> out_norm, node_info.
__global__ void fine_hist_src_kernel(const unsigned char* __restrict__ srcp,
                                     const int* __restrict__ bbase_s,
                                     const int* __restrict__ labels,
                                     float* __restrict__ out_norm,
                                     int2* __restrict__ node_info) {
    __shared__ int cnt[256];
    int b = blockIdx.x, t = threadIdx.x;
    cnt[t] = 0;
    __syncthreads();
    int lo = bbase_s[b], hi = bbase_s[b + 1];
    for (int i = lo + t; i < hi; i += 256)
        atomicAdd(&cnt[srcp[i]], 1);
    __syncthreads();
    int node = b * 256 + t;
    if (node < N_NODES) {
        float on = rsqrtf(fmaxf((float)cnt[t], 1.0f));
        out_norm[node] = on;
        node_info[node] = make_int2(labels[node] << 16, __float_as_int(on));
    }
}

// Merged: dst fine-hist + scan + scatter + S-build + h1 MFMA.
// Block b owns bucket b (nodes b*256..): local histogram -> deg_in, row_off =
// bbase_d[b] + local exclusive prefix (bbase_d[b] IS the global edge prefix);
// scatter esrc; accumulate S[n][label] in LDS fp32; then h1s =
// relu(in_norm*(S@T1t)+b1)*out_norm via MFMA straight from Sl (4 waves x 64 nodes).
__global__ __launch_bounds__(256) void scan_scatter_h1_kernel(
        const int* __restrict__ dstp, const int* __restrict__ bbase_d,
        const int2* __restrict__ node_info,
        const __half* __restrict__ T1t, const float* __restrict__ b1,
        const float* __restrict__ out_norm,
        int* __restrict__ deg_in, int* __restrict__ row_off, float* __restrict__ in_norm,
        unsigned short* __restrict__ esrc, __half* __restrict__ h1s) {
    __shared__ float Sl[256][NLAB];          // 51.2 KB
    __shared__ int cnt[256];
    __shared__ int ro[256];
    __shared__ int cur[256];
    __shared__ int sc[256];
    int t = threadIdx.x, b = blockIdx.x;
    int node = b * 256 + t;
    for (int idx = t; idx < 256 * NLAB; idx += 256) ((float*)Sl)[idx] = 0.0f;
    cnt[t] = 0; cur[t] = 0;
    __syncthreads();
    int lo = bbase_d[b], hi = bbase_d[b + 1];
    // pass 1: per-node in-degree histogram
    for (int k = lo + t; k < hi; k += 256)
        atomicAdd(&cnt[(dstp[k] >> 16) & 0xFF], 1);
    __syncthreads();
    int own = cnt[t];
    sc[t] = own;
    __syncthreads();
    for (int off = 1; off < 256; off <<= 1) {
        int v = sc[t];
        if (t >= off) v += sc[t - off];
        __syncthreads();
        sc[t] = v;
        __syncthreads();
    }
    int r0 = lo + sc[t] - own;   // global row offset
    ro[t] = r0;
    if (node < N_NODES) {
        deg_in[node] = own;
        row_off[node] = r0;
        in_norm[node] = rsqrtf(fmaxf((float)own, 1.0f));
    }
    __syncthreads();
    // pass 2: scatter + S accumulate
    for (int k = lo + t; k < hi; k += 256) {
        int rec = dstp[k];
        int sn = rec & 0xFFFF;
        int nl = (rec >> 16) & 0xFF;
        int r = atomicAdd(&cur[nl], 1);
        esrc[ro[nl] + r] = (unsigned short)sn;
        int2 ni = node_info[sn];
        atomicAdd(&Sl[nl][((unsigned)ni.x) >> 16], __int_as_float(ni.y));
    }
    __syncthreads();
    // pass 3: h1 via MFMA. 4 waves; wave w covers block-local nodes [w*64, w*64+64)
    // in 4 M-tiles of 16. A row=lane&15, k=(lane>>4)*8+i; D col=lane&15,
    // row=(lane>>4)*4+reg (m89/m91-verified).
    const int w = t >> 6, l = t & 63;
    const int lr = l & 15, lg = l >> 4;
#pragma unroll
    for (int mt = 0; mt < 4; ++mt) {
        int mbase = w * 64 + mt * 16;
        f16x8 a[2];
#pragma unroll
        for (int kb = 0; kb < 2; ++kb) {
#pragma unroll
            for (int i = 0; i < 8; ++i) {
                int kk = kb * 32 + lg * 8 + i;
                a[kb][i] = (_Float16)((kk < NLAB) ? Sl[mbase + lr][kk] : 0.0f);
            }
        }
#pragma unroll
        for (int nt = 0; nt < 6; ++nt) {
            f32x4 acc = (f32x4){0.f, 0.f, 0.f, 0.f};
#pragma unroll
            for (int kb = 0; kb < 2; ++kb) {
                f16x8 bfr = *(const f16x8*)(T1t + (nt * 16 + lr) * T1TSTR + kb * 32 + lg * 8);
                acc = __builtin_amdgcn_mfma_f32_16x16x32_f16(a[kb], bfr, acc, 0, 0, 0);
            }
            int col = nt * 16 + lr;
            float bb = b1[col];
#pragma unroll
            for (int r = 0; r < 4; ++r) {
                int mrow = mbase + lg * 4 + r;
                int n = b * 256 + mrow;
                if (n < N_NODES) {
                    float innv = rsqrtf(fmaxf((float)cnt[mrow], 1.0f));
                    float v = fmaxf(innv * acc[r] + bb, 0.f) * out_norm[n];
                    h1s[(size_t)n * HID + col] = __float2half(v);
                }
            }
        }
    }
}

// Fused: layer-2 aggregation (gather h1s fp16 rows -> LDS fp16 A) + MFMA
// layers 2+3. 128 nodes/block, 512 threads. h2 overwrites A in-place (each
// wave owns its 16 rows exclusively). t must be DISJOINT from hs (race fix).
__global__ __launch_bounds__(512) void agg_linear23_kernel(
        const __half* __restrict__ hs, const int* __restrict__ row_off,
        const int* __restrict__ deg, const unsigned short* __restrict__ esrc,
        const float* __restrict__ in_norm, const __half* __restrict__ wprep,
        const float* __restrict__ b2, const float* __restrict__ out_norm,
        __half* __restrict__ t) {
    __shared__ _Float16 Wl[WPREP_N];          // 33.3 KB: W2t [96][104] + W3t [64][104]
    __shared__ _Float16 A[128][WSTRIDE];      // 26.6 KB: agg fp16, then h2 in-place
    const int tid = threadIdx.x;
    {   // stage W2t+W3t (linear uint4 copy)
        const uint4* sp = (const uint4*)wprep;
        uint4* dp = (uint4*)Wl;
        for (int i = tid; i < WPREP_N / 8; i += 512) dp[i] = sp[i];
    }
    const int n0b = blockIdx.x * 128;

    // ---- phase 1: aggregate 128 nodes x 12 chunk-pairs into A ----
    for (int task = tid; task < 128 * 12; task += 512) {
        int m = task / 12;
        int c = task - m * 12;
        int n = n0b + m;
        uint2 rA = make_uint2(0u, 0u), rB = make_uint2(0u, 0u);
        if (n < N_NODES) {
            const __half* p0 = hs + c * 4;
            const __half* p1 = hs + (c + 12) * 4;
            int k = row_off[n];
            int e = k + deg[n];
            float ax = 0.f, ay = 0.f, az = 0.f, aw = 0.f;
            float bx = 0.f, by = 0.f, bz = 0.f, bw = 0.f;
            for (; k + 3 < e; k += 4) {
                size_t r0 = (size_t)esrc[k] * HID;
                size_t r1 = (size_t)esrc[k + 1] * HID;
                size_t r2 = (size_t)esrc[k + 2] * HID;
                size_t r3 = (size_t)esrc[k + 3] * HID;
                uint2 aA = *(const uint2*)(p0 + r0); uint2 bA = *(const uint2*)(p1 + r0);
                uint2 aB = *(const uint2*)(p0 + r1); uint2 bB = *(const uint2*)(p1 + r1);
                uint2 aC = *(const uint2*)(p0 + r2); uint2 bC = *(const uint2*)(p1 + r2);
                uint2 aD = *(const uint2*)(p0 + r3); uint2 bD = *(const uint2*)(p1 + r3);
                float2 f;
                f = h2f(aA.x); ax += f.x; ay += f.y;  f = h2f(aA.y); az += f.x; aw += f.y;
                f = h2f(aB.x); ax += f.x; ay += f.y;  f = h2f(aB.y); az += f.x; aw += f.y;
                f = h2f(aC.x); ax += f.x; ay += f.y;  f = h2f(aC.y); az += f.x; aw += f.y;
                f = h2f(aD.x); ax += f.x; ay += f.y;  f = h2f(aD.y); az += f.x; aw += f.y;
                f = h2f(bA.x); bx += f.x; by += f.y;  f = h2f(bA.y); bz += f.x; bw += f.y;
                f = h2f(bB.x); bx += f.x; by += f.y;  f = h2f(bB.y); bz += f.x; bw += f.y;
                f = h2f(bC.x); bx += f.x; by += f.y;  f = h2f(bC.y); bz += f.x; bw += f.y;
                f = h2f(bD.x); bx += f.x; by += f.y;  f = h2f(bD.y); bz += f.x; bw += f.y;
            }
            for (; k < e; ++k) {
                size_t r0 = (size_t)esrc[k] * HID;
                uint2 aA = *(const uint2*)(p0 + r0); uint2 bA = *(const uint2*)(p1 + r0);
                float2 f;
                f = h2f(aA.x); ax += f.x; ay += f.y;  f = h2f(aA.y); az += f.x; aw += f.y;
                f = h2f(bA.x); bx += f.x; by += f.y;  f = h2f(bA.y); bz += f.x; bw += f.y;
            }
            float nn = in_norm[n];
            rA.x = f2h(ax * nn, ay * nn); rA.y = f2h(az * nn, aw * nn);
            rB.x = f2h(bx * nn, by * nn); rB.y = f2h(bz * nn, bw * nn);
        }
        *(uint2*)(&A[m][c * 4]) = rA;
        *(uint2*)(&A[m][(c + 12) * 4]) = rB;
    }
    __syncthreads();

    // ---- phase 2: MFMA GEMM1 + GEMM2 ----
    const int w = tid >> 6, l = tid & 63;
    const int lr = l & 15, lg = l >> 4;
    const int m0 = w * 16;
    const int n0 = n0b + m0;

    f16x8 a[3];
#pragma unroll
    for (int kb = 0; kb < 3; ++kb)
        a[kb] = *(const f16x8*)(&A[m0 + lr][kb * 32 + lg * 8]);
    f32x4 acc[6];
#pragma unroll
    for (int nt = 0; nt < 6; ++nt) {
        acc[nt] = (f32x4){0.f, 0.f, 0.f, 0.f};
#pragma unroll
        for (int kb = 0; kb < 3; ++kb) {
            f16x8 bfr = *(const f16x8*)(&Wl[(nt * 16 + lr) * WSTRIDE + kb * 32 + lg * 8]);
            acc[nt] = __builtin_amdgcn_mfma_f32_16x16x32_f16(a[kb], bfr, acc[nt], 0, 0, 0);
        }
    }
    float on4[4];
#pragma unroll
    for (int r = 0; r < 4; ++r) {
        int n = n0 + lg * 4 + r; if (n > N_NODES - 1) n = N_NODES - 1;
        on4[r] = out_norm[n];
    }
    asm volatile("s_waitcnt lgkmcnt(0)" ::: "memory");
#pragma unroll
    for (int nt = 0; nt < 6; ++nt) {
        int col = nt * 16 + lr;
        float bb = b2[col];
#pragma unroll
        for (int r = 0; r < 4; ++r) {
            float v = fmaxf(acc[nt][r] + bb, 0.f) * on4[r];
            A[m0 + lg * 4 + r][col] = (_Float16)v;
        }
    }
    asm volatile("s_waitcnt lgkmcnt(0)" ::: "memory");

    f16x8 a2[3];
#pragma unroll
    for (int kb = 0; kb < 3; ++kb)
        a2[kb] = *(const f16x8*)(&A[m0 + lr][kb * 32 + lg * 8]);
#pragma unroll
    for (int nt = 0; nt < 4; ++nt) {
        f32x4 acc2 = (f32x4){0.f, 0.f, 0.f, 0.f};
#pragma unroll
        for (int kb = 0; kb < 3; ++kb) {
            f16x8 bfr = *(const f16x8*)(&Wl[(HID + nt * 16 + lr) * WSTRIDE + kb * 32 + lg * 8]);
            acc2 = __builtin_amdgcn_mfma_f32_16x16x32_f16(a2[kb], bfr, acc2, 0, 0, 0);
        }
        int col = nt * 16 + lr;
        if (col < 4 * TC) {
#pragma unroll
            for (int r = 0; r < 4; ++r) {
                int n = n0 + lg * 4 + r;
                if (n < N_NODES) t[(size_t)n * TSTRIDE + col] = __float2half(acc2[r]);
            }
        }
    }
}

// Final gather over FP16 t (128B-aligned rows, 1 line each).
__global__ void gather_out_kernel(const __half* __restrict__ t, const int* __restrict__ row_off,
                                  const int* __restrict__ deg, const unsigned short* __restrict__ esrc,
                                  const float* __restrict__ in_norm, const float* __restrict__ bias,
                                  float* __restrict__ out) {
    int i = blockIdx.x * blockDim.x + threadIdx.x;
    if (i >= N_NODES * TC) return;
    int n = i / TC;
    int c = i - n * TC;
    const __half* p0 = t + c * 4;
    int k = row_off[n];
    int e = k + deg[n];
    float ax = 0.f, ay = 0.f, az = 0.f, aw = 0.f;
    for (; k + 3 < e; k += 4) {
        size_t r0 = (size_t)esrc[k] * TSTRIDE;
        size_t r1 = (size_t)esrc[k + 1] * TSTRIDE;
        size_t r2 = (size_t)esrc[k + 2] * TSTRIDE;
        size_t r3 = (size_t)esrc[k + 3] * TSTRIDE;
        uint2 v0 = *(const uint2*)(p0 + r0);
        uint2 v1 = *(const uint2*)(p0 + r1);
        uint2 v2 = *(const uint2*)(p0 + r2);
        uint2 v3 = *(const uint2*)(p0 + r3);
        float2 f;
        f = h2f(v0.x); ax += f.x; ay += f.y;  f = h2f(v0.y); az += f.x; aw += f.y;
        f = h2f(v1.x); ax += f.x; ay += f.y;  f = h2f(v1.y); az += f.x; aw += f.y;
        f = h2f(v2.x); ax += f.x; ay += f.y;  f = h2f(v2.y); az += f.x; aw += f.y;
        f = h2f(v3.x); ax += f.x; ay += f.y;  f = h2f(v3.y); az += f.x; aw += f.y;
    }
    for (; k < e; ++k) {
        size_t r0 = (size_t)esrc[k] * TSTRIDE;
        uint2 v0 = *(const uint2*)(p0 + r0);
        float2 f;
        f = h2f(v0.x); ax += f.x; ay += f.y;  f = h2f(v0.y); az += f.x; aw += f.y;
    }
    float nn = in_norm[n];
    int j = c * 4;
    float* op = out + (size_t)n * NLAB + j;   // rows 8B-aligned only -> float2 stores
    float2 lo; lo.x = ax * nn + bias[j];     lo.y = ay * nn + bias[j + 1];
    *(float2*)op = lo;
    if (j + 2 < NLAB) {
        float2 hi; hi.x = az * nn + bias[j + 2]; hi.y = aw * nn + bias[j + 3];
        *(float2*)(op + 2) = hi;
    }
}

static inline int cdiv(long a, int b) { return (int)((a + b - 1) / b); }

extern "C" void kernel_launch(void* const* d_in, const int* in_sizes, int n_in,
                              void* d_out, int out_size, void* d_ws, size_t ws_size,
                              hipStream_t stream) {
    const int*   dep_labels = (const int*)d_in[0];
    const int*   src        = (const int*)d_in[1];
    const int*   dst        = (const int*)d_in[2];
    const float* emb        = (const float*)d_in[3];
    const float* W1 = (const float*)d_in[4]; const float* b1 = (const float*)d_in[5];
    const float* W2 = (const float*)d_in[6]; const float* b2 = (const float*)d_in[7];
    const float* W3 = (const float*)d_in[8]; const float* b3 = (const float*)d_in[9];
    float* out = (float*)d_out;

    // ---- workspace layout (regions 16B aligned) ----
    int* wsp           = (int*)d_ws;
    int* row_off       = wsp;                 wsp += N_NODES;
    int* deg_in        = wsp;                 wsp += N_NODES;
    float* out_norm    = (float*)wsp;         wsp += N_NODES;
    float* in_norm     = (float*)wsp;         wsp += N_NODES;
    int2* node_info    = (int2*)wsp;          wsp += 2 * N_NODES;
    __half* T1t        = (__half*)wsp;        wsp += T1T_N / 2 + 8;
    __half* wprep      = (__half*)wsp;        wsp += WPREP_N / 2;
    unsigned short* esrc = (unsigned short*)wsp; wsp += N_EDGES / 2;  // 1.6 MB
    int* bufA          = wsp;                 wsp += (size_t)N_NODES * HID;   // 19.2 MB
    __half* bufH       = (__half*)wsp;        // h1s (fp16) only
    // Inside bufA:
    //   tbuf: [0 .. 1.6M ints) — t (fp16 stride 64), written k6, read k7.
    //   CSR temps overlap tbuf region only (all < 1.26M ints, dead after k5).
    __half* tbuf  = (__half*)bufA;
    int* histd    = bufA;                     // [NBP][256]
    int* hists    = histd + NBP * 256;
    int* blkrel_d = hists + NBP * 256;
    int* blkrel_s = blkrel_d + NBP * 256;
    int* bbase_d  = blkrel_s + NBP * 256;     // [256]
    int* bbase_s  = bbase_d + 256;            // [256]
    int* dstp     = bbase_s + 256;            // [N_EDGES] -> ends ~1.056M
    unsigned char* srcp = (unsigned char*)(dstp + N_EDGES);  // [N_EDGES] bytes -> ends ~1.256M

    const int B = 256;

    // ---- CSR build: no global atomics anywhere ----
    coarse_hist_kernel<<<NBP + T1TB + WPREPB, B, 0, stream>>>(src, dst, histd, hists,
                                                              emb, W1, T1t, W2, W3, wprep);
    coarse_scan_kernel<<<2, B, 0, stream>>>(histd, hists, blkrel_d, blkrel_s, bbase_d, bbase_s);
    partition_kernel<<<NBP, B, 0, stream>>>(src, dst, blkrel_d, blkrel_s, bbase_d, bbase_s,
                                            dstp, srcp);
    fine_hist_src_kernel<<<NBUCK, B, 0, stream>>>(srcp, bbase_s, dep_labels,
                                                  out_norm, node_info);
    // dst fine-hist + scan + scatter + S + h1 MFMA, all in one kernel
    scan_scatter_h1_kernel<<<NBUCK, B, 0, stream>>>(dstp, bbase_d, node_info, T1t, b1,
                                                    out_norm, deg_in, row_off, in_norm,
                                                    esrc, bufH);

    // Layer 2 aggregate + layers 2+3 MFMA transform, fused: h1s -> t (in bufA)
    agg_linear23_kernel<<<NMFMA, 512, 0, stream>>>(
        bufH, row_off, deg_in, esrc, in_norm, wprep, b2, out_norm, tbuf);

    // Final gather + bias (fp16 t -> fp32 out)
    gather_out_kernel<<<cdiv((long)N_NODES * TC, B), B, 0, stream>>>(
        tbuf, row_off, deg_in, esrc, in_norm, b3, out);
}

// Round 12
// 185.423 us; speedup vs baseline: 1.0882x; 1.0882x over previous
//
#include <hip/hip_runtime.h>
#include <hip/hip_fp16.h>

// GCN 3-layer, CSR-gather, low-rank L1 + fused L2/L3 transform.
//   CSR build GLOBAL-ATOMIC-FREE (two-level counting sort, LDS atomics only).
//   R11: LATENCY FIX — scan_scatter_h1 was 45us at 6.9% occupancy / 4.7% VALU
//     (196 blocks x 256thr = 1 wave/SIMD, barrier-chained). All CSR kernels
//     widened to 1024 threads (edge passes 16->4 iters; h1 pass: 16 waves x
//     one 16-row M-tile). Algorithm/rounding unchanged.
//   R10: scan_scatter absorbs dst fine-hist (row_off = bbase_d[b] + local
//     prefix) and the h1 layer (S@T1t MFMA straight from LDS Sl).
//   R8: layer-1 low-rank over labels (S[n][l] = sum out_norm over in-edges).
//   L2+L3 fused: agg -> LDS fp16 A, MFMA 16x16x32_f16 (fp32 acc),
//     W2t/W3t fp16 LDS stride 104, h2 in-place per-wave, t fp16 stride 64
//     in bufA (disjoint from h1s — R6 race fix).
//   out = in_norm*gather(t fp16) + b3
#define N_NODES 50000
#define N_EDGES 800000
#define EMB     64
#define HID     96
#define NLAB    50
#define TSTRIDE 64                         // t row stride (halfs): 128B line-aligned
#define TC      13                         // gather chunks over t (cols 0..51)
#define NBP     256                        // partition blocks
#define EPB     ((N_EDGES + NBP - 1) / NBP)  // 3125 edges per block
#define NBUCK   196                        // node buckets of 256 (covers 50176)
#define WSTRIDE 104                        // W2t/W3t/A LDS row stride (halfs)
#define WPREP_N (160 * WSTRIDE)            // 96 W2t rows + 64 W3t rows
#define WPREPB  ((WPREP_N + 1023) / 1024)  // 17
#define T1TSTR  72                         // T1t row stride (halfs)
#define T1T_N   (HID * T1TSTR)             // 96 rows x 72
#define T1TB    ((T1T_N + 1023) / 1024)    // 7
#define NMFMA   ((N_NODES + 127) / 128)    // 392 blocks of 128 nodes

typedef _Float16 f16x8 __attribute__((ext_vector_type(8)));
typedef float f32x4 __attribute__((ext_vector_type(4)));

__device__ __forceinline__ float2 h2f(unsigned u) {
    __half2 h = *reinterpret_cast<__half2*>(&u);
    return __half22float2(h);
}
__device__ __forceinline__ unsigned f2h(float a, float b) {
    __half2 h = __floats2half2_rn(a, b);
    return *reinterpret_cast<unsigned*>(&h);
}

// Per-block coarse histograms (dst>>8, src>>8) via LDS atomics, 1024 threads.
// Tail blocks: T1t fp16 prep, then W2t/W3t fp16 prep.
__global__ __launch_bounds__(1024) void coarse_hist_kernel(
        const int* __restrict__ src, const int* __restrict__ dst,
        int* __restrict__ histd, int* __restrict__ hists,
        const float* __restrict__ emb, const float* __restrict__ W1,
        __half* __restrict__ T1t,
        const float* __restrict__ W2, const float* __restrict__ W3,
        __half* __restrict__ wprep) {
    int b = blockIdx.x, t = threadIdx.x;
    if (b < NBP) {
        __shared__ int hd[256], hs[256];
        if (t < 256) { hd[t] = 0; hs[t] = 0; }
        __syncthreads();
        int hi = min(b * EPB + EPB, N_EDGES);
        for (int i = b * EPB + t; i < hi; i += 1024) {
            atomicAdd(&hd[((unsigned)dst[i]) >> 8], 1);
            atomicAdd(&hs[((unsigned)src[i]) >> 8], 1);
        }
        __syncthreads();
        if (t < 256) {
            histd[b * 256 + t] = hd[t];
            hists[b * 256 + t] = hs[t];
        }
    } else if (b < NBP + T1TB) {
        int i = (b - NBP) * 1024 + t;
        if (i < T1T_N) {
            int j = i / T1TSTR, l = i - j * T1TSTR;
            float sum = 0.0f;
            if (l < NLAB) {
#pragma unroll
                for (int m = 0; m < EMB; ++m) sum += emb[l * EMB + m] * W1[m * HID + j];
            }
            T1t[i] = __float2half(sum);
        }
    } else {
        // wprep rows 0..95: W2t (j over HID); rows 96..159: W3t (j over 64)
        int i = (b - NBP - T1TB) * 1024 + t;
        if (i < WPREP_N) {
            int j = i / WSTRIDE, kk = i - j * WSTRIDE;
            float v = 0.0f;
            if (kk < HID) {
                if (j < HID) v = W2[kk * HID + j];
                else { int jj = j - HID; if (jj < NLAB) v = W3[kk * NLAB + jj]; }
            }
            wprep[i] = __float2half(v);
        }
    }
}

// Block 0: dst side; block 1: src side. Thread t owns bucket t.
__global__ void coarse_scan_kernel(const int* __restrict__ histd, const int* __restrict__ hists,
                                   int* __restrict__ blkrel_d, int* __restrict__ blkrel_s,
                                   int* __restrict__ bbase_d, int* __restrict__ bbase_s) {
    __shared__ int sh[256];
    int t = threadIdx.x;
    const int* hist = blockIdx.x ? hists : histd;
    int* blkrel     = blockIdx.x ? blkrel_s : blkrel_d;
    int* bbase      = blockIdx.x ? bbase_s : bbase_d;
    int run = 0;
#pragma unroll 16
    for (int b = 0; b < NBP; ++b) {
        blkrel[b * 256 + t] = run;
        run += hist[b * 256 + t];
    }
    sh[t] = run;
    __syncthreads();
    for (int off = 1; off < 256; off <<= 1) {
        int v = sh[t];
        if (t >= off) v += sh[t - off];
        __syncthreads();
        sh[t] = v;
        __syncthreads();
    }
    bbase[t] = sh[t] - run;   // exclusive bucket base
}

// Scatter edges into bucket-partitioned arrays via LDS cursors, 1024 threads.
// dstp rec = src | (dst&255)<<16 ; srcp rec = (byte) src&255.
__global__ __launch_bounds__(1024) void partition_kernel(
        const int* __restrict__ src, const int* __restrict__ dst,
        const int* __restrict__ blkrel_d, const int* __restrict__ blkrel_s,
        const int* __restrict__ bbase_d, const int* __restrict__ bbase_s,
        int* __restrict__ dstp, unsigned char* __restrict__ srcp) {
    __shared__ int curd[256], curs[256];
    int b = blockIdx.x, t = threadIdx.x;
    if (t < 256) {
        curd[t] = bbase_d[t] + blkrel_d[b * 256 + t];
        curs[t] = bbase_s[t] + blkrel_s[b * 256 + t];
    }
    __syncthreads();
    int hi = min(b * EPB + EPB, N_EDGES);
    for (int i = b * EPB + t; i < hi; i += 1024) {
        int d = dst[i], s = src[i];
        int pd = atomicAdd(&curd[((unsigned)d) >> 8], 1);
        dstp[pd] = s | ((d & 0xFF) << 16);
        int ps = atomicAdd(&curs[((unsigned)s) >> 8], 1);
        srcp[ps] = (unsigned char)(s & 0xFF);
    }
}

// Src-side fine histogram only: deg_out -> out_norm, node_info. 1024 threads.
__global__ __launch_bounds__(1024) void fine_hist_src_kernel(
        const unsigned char* __restrict__ srcp,
        const int* __restrict__ bbase_s,
        const int* __restrict__ labels,
        float* __restrict__ out_norm,
        int2* __restrict__ node_info) {
    __shared__ int cnt[256];
    int b = blockIdx.x, t = threadIdx.x;
    if (t < 256) cnt[t] = 0;
    __syncthreads();
    int lo = bbase_s[b], hi = bbase_s[b + 1];
    for (int i = lo + t; i < hi; i += 1024)
        atomicAdd(&cnt[srcp[i]], 1);
    __syncthreads();
    int node = b * 256 + t;
    if (t < 256 && node < N_NODES) {
        float on = rsqrtf(fmaxf((float)cnt[t], 1.0f));
        out_norm[node] = on;
        node_info[node] = make_int2(labels[node] << 16, __float_as_int(on));
    }
}

// Merged: dst fine-hist + scan + scatter + S-build + h1 MFMA. 1024 threads:
// edge passes stride 1024; 256-wide scan on t<256; h1 = 16 waves x one
// 16-row M-tile. row_off = bbase_d[b] + local exclusive prefix.
__global__ __launch_bounds__(1024) void scan_scatter_h1_kernel(
        const int* __restrict__ dstp, const int* __restrict__ bbase_d,
        const int2* __restrict__ node_info,
        const __half* __restrict__ T1t, const float* __restrict__ b1,
        const float* __restrict__ out_norm,
        int* __restrict__ deg_in, int* __restrict__ row_off, float* __restrict__ in_norm,
        unsigned short* __restrict__ esrc, __half* __restrict__ h1s) {
    __shared__ float Sl[256][NLAB];          // 51.2 KB
    __shared__ int cnt[256];
    __shared__ int ro[256];
    __shared__ int cur[256];
    __shared__ int sc[256];
    int t = threadIdx.x, b = blockIdx.x;
    int node = b * 256 + t;
    for (int idx = t; idx < 256 * NLAB; idx += 1024) ((float*)Sl)[idx] = 0.0f;
    if (t < 256) { cnt[t] = 0; cur[t] = 0; }
    __syncthreads();
    int lo = bbase_d[b], hi = bbase_d[b + 1];
    // pass 1: per-node in-degree histogram
    for (int k = lo + t; k < hi; k += 1024)
        atomicAdd(&cnt[(dstp[k] >> 16) & 0xFF], 1);
    __syncthreads();
    int own = (t < 256) ? cnt[t] : 0;
    if (t < 256) sc[t] = own;
    __syncthreads();
    for (int off = 1; off < 256; off <<= 1) {
        int v = 0;
        if (t < 256) { v = sc[t]; if (t >= off) v += sc[t - off]; }
        __syncthreads();
        if (t < 256) sc[t] = v;
        __syncthreads();
    }
    if (t < 256) {
        int r0 = lo + sc[t] - own;   // global row offset
        ro[t] = r0;
        if (node < N_NODES) {
            deg_in[node] = own;
            row_off[node] = r0;
            in_norm[node] = rsqrtf(fmaxf((float)own, 1.0f));
        }
    }
    __syncthreads();
    // pass 2: scatter + S accumulate
    for (int k = lo + t; k < hi; k += 1024) {
        int rec = dstp[k];
        int sn = rec & 0xFFFF;
        int nl = (rec >> 16) & 0xFF;
        int r = atomicAdd(&cur[nl], 1);
        esrc[ro[nl] + r] = (unsigned short)sn;
        int2 ni = node_info[sn];
        atomicAdd(&Sl[nl][((unsigned)ni.x) >> 16], __int_as_float(ni.y));
    }
    __syncthreads();
    // pass 3: h1 via MFMA. 16 waves; wave w handles block-local rows
    // [w*16, w*16+16). A row=lane&15, k=(lane>>4)*8+i; D col=lane&15,
    // row=(lane>>4)*4+reg (m89/m91-verified).
    const int w = t >> 6, l = t & 63;
    const int lr = l & 15, lg = l >> 4;
    const int mbase = w * 16;
    f16x8 a[2];
#pragma unroll
    for (int kb = 0; kb < 2; ++kb) {
#pragma unroll
        for (int i = 0; i < 8; ++i) {
            int kk = kb * 32 + lg * 8 + i;
            a[kb][i] = (_Float16)((kk < NLAB) ? Sl[mbase + lr][kk] : 0.0f);
        }
    }
#pragma unroll
    for (int nt = 0; nt < 6; ++nt) {
        f32x4 acc = (f32x4){0.f, 0.f, 0.f, 0.f};
#pragma unroll
        for (int kb = 0; kb < 2; ++kb) {
            f16x8 bfr = *(const f16x8*)(T1t + (nt * 16 + lr) * T1TSTR + kb * 32 + lg * 8);
            acc = __builtin_amdgcn_mfma_f32_16x16x32_f16(a[kb], bfr, acc, 0, 0, 0);
        }
        int col = nt * 16 + lr;
        float bb = b1[col];
#pragma unroll
        for (int r = 0; r < 4; ++r) {
            int mrow = mbase + lg * 4 + r;
            int n = b * 256 + mrow;
            if (n < N_NODES) {
                float innv = rsqrtf(fmaxf((float)cnt[mrow], 1.0f));
                float v = fmaxf(innv * acc[r] + bb, 0.f) * out_norm[n];
                h1s[(size_t)n * HID + col] = __float2half(v);
            }
        }
    }
}

// Fused: layer-2 aggregation (gather h1s fp16 rows -> LDS fp16 A) + MFMA
// layers 2+3. 128 nodes/block, 512 threads. h2 overwrites A in-place (each
// wave owns its 16 rows exclusively). t must be DISJOINT from hs (race fix).
__global__ __launch_bounds__(512) void agg_linear23_kernel(
        const __half* __restrict__ hs, const int* __restrict__ row_off,
        const int* __restrict__ deg, const unsigned short* __restrict__ esrc,
        const float* __restrict__ in_norm, const __half* __restrict__ wprep,
        const float* __restrict__ b2, const float* __restrict__ out_norm,
        __half* __restrict__ t) {
    __shared__ _Float16 Wl[WPREP_N];          // 33.3 KB: W2t [96][104] + W3t [64][104]
    __shared__ _Float16 A[128][WSTRIDE];      // 26.6 KB: agg fp16, then h2 in-place
    const int tid = threadIdx.x;
    {   // stage W2t+W3t (linear uint4 copy)
        const uint4* sp = (const uint4*)wprep;
        uint4* dp = (uint4*)Wl;
        for (int i = tid; i < WPREP_N / 8; i += 512) dp[i] = sp[i];
    }
    const int n0b = blockIdx.x * 128;

    // ---- phase 1: aggregate 128 nodes x 12 chunk-pairs into A ----
    for (int task = tid; task < 128 * 12; task += 512) {
        int m = task / 12;
        int c = task - m * 12;
        int n = n0b + m;
        uint2 rA = make_uint2(0u, 0u), rB = make_uint2(0u, 0u);
        if (n < N_NODES) {
            const __half* p0 = hs + c * 4;
            const __half* p1 = hs + (c + 12) * 4;
            int k = row_off[n];
            int e = k + deg[n];
            float ax = 0.f, ay = 0.f, az = 0.f, aw = 0.f;
            float bx = 0.f, by = 0.f, bz = 0.f, bw = 0.f;
            for (; k + 3 < e; k += 4) {
                size_t r0 = (size_t)esrc[k] * HID;
                size_t r1 = (size_t)esrc[k + 1] * HID;
                size_t r2 = (size_t)esrc[k + 2] * HID;
                size_t r3 = (size_t)esrc[k + 3] * HID;
                uint2 aA = *(const uint2*)(p0 + r0); uint2 bA = *(const uint2*)(p1 + r0);
                uint2 aB = *(const uint2*)(p0 + r1); uint2 bB = *(const uint2*)(p1 + r1);
                uint2 aC = *(const uint2*)(p0 + r2); uint2 bC = *(const uint2*)(p1 + r2);
                uint2 aD = *(const uint2*)(p0 + r3); uint2 bD = *(const uint2*)(p1 + r3);
                float2 f;
                f = h2f(aA.x); ax += f.x; ay += f.y;  f = h2f(aA.y); az += f.x; aw += f.y;
                f = h2f(aB.x); ax += f.x; ay += f.y;  f = h2f(aB.y); az += f.x; aw += f.y;
                f = h2f(aC.x); ax += f.x; ay += f.y;  f = h2f(aC.y); az += f.x; aw += f.y;
                f = h2f(aD.x); ax += f.x; ay += f.y;  f = h2f(aD.y); az += f.x; aw += f.y;
                f = h2f(bA.x); bx += f.x; by += f.y;  f = h2f(bA.y); bz += f.x; bw += f.y;
                f = h2f(bB.x); bx += f.x; by += f.y;  f = h2f(bB.y); bz += f.x; bw += f.y;
                f = h2f(bC.x); bx += f.x; by += f.y;  f = h2f(bC.y); bz += f.x; bw += f.y;
                f = h2f(bD.x); bx += f.x; by += f.y;  f = h2f(bD.y); bz += f.x; bw += f.y;
            }
            for (; k < e; ++k) {
                size_t r0 = (size_t)esrc[k] * HID;
                uint2 aA = *(const uint2*)(p0 + r0); uint2 bA = *(const uint2*)(p1 + r0);
                float2 f;
                f = h2f(aA.x); ax += f.x; ay += f.y;  f = h2f(aA.y); az += f.x; aw += f.y;
                f = h2f(bA.x); bx += f.x; by += f.y;  f = h2f(bA.y); bz += f.x; bw += f.y;
            }
            float nn = in_norm[n];
            rA.x = f2h(ax * nn, ay * nn); rA.y = f2h(az * nn, aw * nn);
            rB.x = f2h(bx * nn, by * nn); rB.y = f2h(bz * nn, bw * nn);
        }
        *(uint2*)(&A[m][c * 4]) = rA;
        *(uint2*)(&A[m][(c + 12) * 4]) = rB;
    }
    __syncthreads();

    // ---- phase 2: MFMA GEMM1 + GEMM2 ----
    const int w = tid >> 6, l = tid & 63;
    const int lr = l & 15, lg = l >> 4;
    const int m0 = w * 16;
    const int n0 = n0b + m0;

    f16x8 a[3];
#pragma unroll
    for (int kb = 0; kb < 3; ++kb)
        a[kb] = *(const f16x8*)(&A[m0 + lr][kb * 32 + lg * 8]);
    f32x4 acc[6];
#pragma unroll
    for (int nt = 0; nt < 6; ++nt) {
        acc[nt] = (f32x4){0.f, 0.f, 0.f, 0.f};
#pragma unroll
        for (int kb = 0; kb < 3; ++kb) {
            f16x8 bfr = *(const f16x8*)(&Wl[(nt * 16 + lr) * WSTRIDE + kb * 32 + lg * 8]);
            acc[nt] = __builtin_amdgcn_mfma_f32_16x16x32_f16(a[kb], bfr, acc[nt], 0, 0, 0);
        }
    }
    float on4[4];
#pragma unroll
    for (int r = 0; r < 4; ++r) {
        int n = n0 + lg * 4 + r; if (n > N_NODES - 1) n = N_NODES - 1;
        on4[r] = out_norm[n];
    }
    asm volatile("s_waitcnt lgkmcnt(0)" ::: "memory");
#pragma unroll
    for (int nt = 0; nt < 6; ++nt) {
        int col = nt * 16 + lr;
        float bb = b2[col];
#pragma unroll
        for (int r = 0; r < 4; ++r) {
            float v = fmaxf(acc[nt][r] + bb, 0.f) * on4[r];
            A[m0 + lg * 4 + r][col] = (_Float16)v;
        }
    }
    asm volatile("s_waitcnt lgkmcnt(0)" ::: "memory");

    f16x8 a2[3];
#pragma unroll
    for (int kb = 0; kb < 3; ++kb)
        a2[kb] = *(const f16x8*)(&A[m0 + lr][kb * 32 + lg * 8]);
#pragma unroll
    for (int nt = 0; nt < 4; ++nt) {
        f32x4 acc2 = (f32x4){0.f, 0.f, 0.f, 0.f};
#pragma unroll
        for (int kb = 0; kb < 3; ++kb) {
            f16x8 bfr = *(const f16x8*)(&Wl[(HID + nt * 16 + lr) * WSTRIDE + kb * 32 + lg * 8]);
            acc2 = __builtin_amdgcn_mfma_f32_16x16x32_f16(a2[kb], bfr, acc2, 0, 0, 0);
        }
        int col = nt * 16 + lr;
        if (col < 4 * TC) {
#pragma unroll
            for (int r = 0; r < 4; ++r) {
                int n = n0 + lg * 4 + r;
                if (n < N_NODES) t[(size_t)n * TSTRIDE + col] = __float2half(acc2[r]);
            }
        }
    }
}

// Final gather over FP16 t (128B-aligned rows, 1 line each).
__global__ void gather_out_kernel(const __half* __restrict__ t, const int* __restrict__ row_off,
                                  const int* __restrict__ deg, const unsigned short* __restrict__ esrc,
                                  const float* __restrict__ in_norm, const float* __restrict__ bias,
                                  float* __restrict__ out) {
    int i = blockIdx.x * blockDim.x + threadIdx.x;
    if (i >= N_NODES * TC) return;
    int n = i / TC;
    int c = i - n * TC;
    const __half* p0 = t + c * 4;
    int k = row_off[n];
    int e = k + deg[n];
    float ax = 0.f, ay = 0.f, az = 0.f, aw = 0.f;
    for (; k + 3 < e; k += 4) {
        size_t r0 = (size_t)esrc[k] * TSTRIDE;
        size_t r1 = (size_t)esrc[k + 1] * TSTRIDE;
        size_t r2 = (size_t)esrc[k + 2] * TSTRIDE;
        size_t r3 = (size_t)esrc[k + 3] * TSTRIDE;
        uint2 v0 = *(const uint2*)(p0 + r0);
        uint2 v1 = *(const uint2*)(p0 + r1);
        uint2 v2 = *(const uint2*)(p0 + r2);
        uint2 v3 = *(const uint2*)(p0 + r3);
        float2 f;
        f = h2f(v0.x); ax += f.x; ay += f.y;  f = h2f(v0.y); az += f.x; aw += f.y;
        f = h2f(v1.x); ax += f.x; ay += f.y;  f = h2f(v1.y); az += f.x; aw += f.y;
        f = h2f(v2.x); ax += f.x; ay += f.y;  f = h2f(v2.y); az += f.x; aw += f.y;
        f = h2f(v3.x); ax += f.x; ay += f.y;  f = h2f(v3.y); az += f.x; aw += f.y;
    }
    for (; k < e; ++k) {
        size_t r0 = (size_t)esrc[k] * TSTRIDE;
        uint2 v0 = *(const uint2*)(p0 + r0);
        float2 f;
        f = h2f(v0.x); ax += f.x; ay += f.y;  f = h2f(v0.y); az += f.x; aw += f.y;
    }
    float nn = in_norm[n];
    int j = c * 4;
    float* op = out + (size_t)n * NLAB + j;   // rows 8B-aligned only -> float2 stores
    float2 lo; lo.x = ax * nn + bias[j];     lo.y = ay * nn + bias[j + 1];
    *(float2*)op = lo;
    if (j + 2 < NLAB) {
        float2 hi; hi.x = az * nn + bias[j + 2]; hi.y = aw * nn + bias[j + 3];
        *(float2*)(op + 2) = hi;
    }
}

static inline int cdiv(long a, int b) { return (int)((a + b - 1) / b); }

extern "C" void kernel_launch(void* const* d_in, const int* in_sizes, int n_in,
                              void* d_out, int out_size, void* d_ws, size_t ws_size,
                              hipStream_t stream) {
    const int*   dep_labels = (const int*)d_in[0];
    const int*   src        = (const int*)d_in[1];
    const int*   dst        = (const int*)d_in[2];
    const float* emb        = (const float*)d_in[3];
    const float* W1 = (const float*)d_in[4]; const float* b1 = (const float*)d_in[5];
    const float* W2 = (const float*)d_in[6]; const float* b2 = (const float*)d_in[7];
    const float* W3 = (const float*)d_in[8]; const float* b3 = (const float*)d_in[9];
    float* out = (float*)d_out;

    // ---- workspace layout (regions 16B aligned) ----
    int* wsp           = (int*)d_ws;
    int* row_off       = wsp;                 wsp += N_NODES;
    int* deg_in        = wsp;                 wsp += N_NODES;
    float* out_norm    = (float*)wsp;         wsp += N_NODES;
    float* in_norm     = (float*)wsp;         wsp += N_NODES;
    int2* node_info    = (int2*)wsp;          wsp += 2 * N_NODES;
    __half* T1t        = (__half*)wsp;        wsp += T1T_N / 2 + 8;
    __half* wprep      = (__half*)wsp;        wsp += WPREP_N / 2;
    unsigned short* esrc = (unsigned short*)wsp; wsp += N_EDGES / 2;  // 1.6 MB
    int* bufA          = wsp;                 wsp += (size_t)N_NODES * HID;   // 19.2 MB
    __half* bufH       = (__half*)wsp;        // h1s (fp16) only
    // Inside bufA:
    //   tbuf: [0 .. 1.6M ints) — t (fp16 stride 64), written k6, read k7.
    //   CSR temps overlap tbuf region only (all < 1.26M ints, dead after k5).
    __half* tbuf  = (__half*)bufA;
    int* histd    = bufA;                     // [NBP][256]
    int* hists    = histd + NBP * 256;
    int* blkrel_d = hists + NBP * 256;
    int* blkrel_s = blkrel_d + NBP * 256;
    int* bbase_d  = blkrel_s + NBP * 256;     // [256]
    int* bbase_s  = bbase_d + 256;            // [256]
    int* dstp     = bbase_s + 256;            // [N_EDGES] -> ends ~1.056M
    unsigned char* srcp = (unsigned char*)(dstp + N_EDGES);  // [N_EDGES] bytes -> ends ~1.256M

    const int B = 256;

    // ---- CSR build: no global atomics anywhere; all blocks widened to 1024 ----
    coarse_hist_kernel<<<NBP + T1TB + WPREPB, 1024, 0, stream>>>(src, dst, histd, hists,
                                                                 emb, W1, T1t, W2, W3, wprep);
    coarse_scan_kernel<<<2, B, 0, stream>>>(histd, hists, blkrel_d, blkrel_s, bbase_d, bbase_s);
    partition_kernel<<<NBP, 1024, 0, stream>>>(src, dst, blkrel_d, blkrel_s, bbase_d, bbase_s,
                                               dstp, srcp);
    fine_hist_src_kernel<<<NBUCK, 1024, 0, stream>>>(srcp, bbase_s, dep_labels,
                                                     out_norm, node_info);
    // dst fine-hist + scan + scatter + S + h1 MFMA, one kernel, 16 waves/block
    scan_scatter_h1_kernel<<<NBUCK, 1024, 0, stream>>>(dstp, bbase_d, node_info, T1t, b1,
                                                       out_norm, deg_in, row_off, in_norm,
                                                       esrc, bufH);

    // Layer 2 aggregate + layers 2+3 MFMA transform, fused: h1s -> t (in bufA)
    agg_linear23_kernel<<<NMFMA, 512, 0, stream>>>(
        bufH, row_off, deg_in, esrc, in_norm, wprep, b2, out_norm, tbuf);

    // Final gather + bias (fp16 t -> fp32 out)
    gather_out_kernel<<<cdiv((long)N_NODES * TC, B), B, 0, stream>>>(
        tbuf, row_off, deg_in, esrc, in_norm, b3, out);
}